// Round 10
// baseline (3867.155 us; speedup 1.0000x reference)
//
#include <hip/hip_runtime.h>
#include <hip/hip_bf16.h>

#define NUM_LABELS 64
#define ENC_DIM 256
#define CC 128
#define C2 256
#define OUT_DIM 512
#define NLAYERS 5
#define MAX_T 48
#define BATCH 8
#define T_ENC 64
#define LAB_PAD 0
#define LAB_START 5
#define LAB_STOP 6

#define AGENT __HIP_MEMORY_SCOPE_AGENT

__device__ __forceinline__ float dot4(float4 wv, float4 av) {
    return wv.x * av.x + wv.y * av.y + wv.z * av.z + wv.w * av.w;
}

// release fence + one arrival tick (t0)
__device__ __forceinline__ void sync_signal(int* ctr, int t) {
    __builtin_amdgcn_fence(__ATOMIC_RELEASE, "agent");
    if (t == 0) __hip_atomic_fetch_add(ctr, 1, __ATOMIC_RELAXED, AGENT);
}
// spin until all 8 wgs of this element arrived, then acquire + block barrier
__device__ __forceinline__ void sync_wait(int* ctr, int t, int target) {
    if (t == 0) {
        while (__hip_atomic_load(ctr, __ATOMIC_RELAXED, AGENT) < target) {}
    }
    __builtin_amdgcn_fence(__ATOMIC_ACQUIRE, "agent");
    __syncthreads();
}

// ---------------------------------------------------------------------------
// Kernel A: precompute E2[l] = embed[l]@w_in + b_in (64x256)
//           encp[b,k] = enc[b,:,k]@w_enc + b_enc (8x48x256)
// ---------------------------------------------------------------------------
__global__ __launch_bounds__(256) void pre_kernel(
    const float* __restrict__ enc, const float* __restrict__ embed,
    const float* __restrict__ w_in, const float* __restrict__ b_in,
    const float* __restrict__ w_enc, const float* __restrict__ b_enc,
    float* __restrict__ E2, float* __restrict__ encp)
{
    const int t = threadIdx.x;
    const int blk = blockIdx.x;
    if (blk < NUM_LABELS) {
        float acc = b_in[t];
        const float* e = embed + blk * C2;
        for (int j = 0; j < C2; ++j) acc += e[j] * w_in[j * C2 + t];
        E2[blk * C2 + t] = acc;
    } else {
        const int idx = blk - NUM_LABELS;
        const int b = idx / MAX_T;
        const int k = idx % MAX_T;
        float acc = b_enc[t];
        const float* ecol = enc + b * ENC_DIM * T_ENC + k;
        for (int c = 0; c < ENC_DIM; ++c) acc += ecol[c * T_ENC] * w_enc[c * C2 + t];
        encp[idx * C2 + t] = acc;
    }
}

// ---------------------------------------------------------------------------
// Kernel B: uniform prefix chain -> h0 (5 x 128) fp32
// ---------------------------------------------------------------------------
__global__ __launch_bounds__(256) void prefix_kernel(
    const float* __restrict__ embed, const float* __restrict__ w_in,
    const float* __restrict__ b_in,  const float* __restrict__ b_enc,
    const float* __restrict__ w1,    const float* __restrict__ b1,
    const float* __restrict__ wd,    const float* __restrict__ bd,
    const float* __restrict__ w2,    const float* __restrict__ b2,
    float* __restrict__ h0out)
{
    const int t = threadIdx.x;
    __shared__ float x[C2];
    __shared__ float r[C2];
    __shared__ float h[CC];
    __shared__ float hr[CC];

    {
        float acc = b_in[t] + b_enc[t];
        const float* e = embed + LAB_PAD * C2;
        for (int j = 0; j < C2; ++j) acc += e[j] * w_in[j * C2 + t];
        x[t] = acc;
    }
    __syncthreads();

    for (int i = 0; i < NLAYERS; ++i) {
        r[t] = fmaxf(x[t], 0.f);
        __syncthreads();
        if (t < CC) {
            float a = b1[i * CC + t];
            const float* W = w1 + (i * C2) * CC + t;
            for (int j = 0; j < C2; ++j) a += r[j] * W[j * CC];
            float hv = fmaxf(a, 0.f);
            h[t] = hv;
            h0out[i * CC + t] = hv;
        }
        __syncthreads();
        if (t < CC) {
            float a = bd[i * CC + t];
            const float* W0 = wd + ((i * 3 + 0) * CC) * CC + t;
            const float* W1 = wd + ((i * 3 + 1) * CC) * CC + t;
            const float* W2 = wd + ((i * 3 + 2) * CC) * CC + t;
            for (int c = 0; c < CC; ++c)
                a += h[c] * (W0[c * CC] + W1[c * CC] + W2[c * CC]);
            hr[t] = fmaxf(a, 0.f);
        }
        __syncthreads();
        {
            float a = b2[i * C2 + t];
            const float* W = w2 + (i * CC) * C2 + t;
            for (int c = 0; c < CC; ++c) a += hr[c] * W[c * C2];
            x[t] += a;
        }
        __syncthreads();
    }
}

// ---------------------------------------------------------------------------
// Repack: slice-major float4 chunk layouts for the 8-way sliced decode.
// Slice s base = s*23040 f4. Layer i: A at i*3584, B at +1024, C at +2560.
// D at 17920, E at 22016. Chunk c = m*256 + t; holds 4 input-rows x 1 out-col.
// ---------------------------------------------------------------------------
__global__ __launch_bounds__(256) void repack_w1_kernel(
    const float* __restrict__ src, float4* __restrict__ dst)  // (5,256,128)
{
    const int p = blockIdx.x * 256 + threadIdx.x;   // < 40960
    const int si = p >> 10, c = p & 1023;
    const int s = si / 5, i = si % 5;
    const int m = c >> 8, tt = c & 255;
    const int g = tt >> 4, o = tt & 15;
    const float* b = src + (i * 256 + g * 16 + m * 4) * 128 + s * 16 + o;
    float4 v; v.x = b[0]; v.y = b[128]; v.z = b[256]; v.w = b[384];
    dst[s * 23040 + i * 3584 + c] = v;
}

__global__ __launch_bounds__(256) void repack_wd_kernel(
    const float* __restrict__ src, float4* __restrict__ dst)  // (5,3,128,128)
{
    const int p = blockIdx.x * 256 + threadIdx.x;   // < 61440
    const int si = p / 1536, c = p % 1536;
    const int s = si / 5, i = si % 5;
    const int u = c >> 8, tt = c & 255;
    const int tap = u >> 1, m = u & 1;
    const int g = tt >> 4, o = tt & 15;
    const float* b = src + ((i * 3 + tap) * 128 + g * 8 + m * 4) * 128 + s * 16 + o;
    float4 v; v.x = b[0]; v.y = b[128]; v.z = b[256]; v.w = b[384];
    dst[s * 23040 + i * 3584 + 1024 + c] = v;
}

__global__ __launch_bounds__(256) void repack_w2_kernel(
    const float* __restrict__ src, float4* __restrict__ dst)  // (5,128,256)
{
    const int p = blockIdx.x * 256 + threadIdx.x;   // < 40960
    const int si = p >> 10, c = p & 1023;
    const int s = si / 5, i = si % 5;
    const int m = c >> 8, tt = c & 255;
    const int g = tt >> 5, o = tt & 31;
    const float* b = src + (i * 128 + g * 16 + m * 4) * 256 + s * 32 + o;
    float4 v; v.x = b[0]; v.y = b[256]; v.z = b[512]; v.w = b[768];
    dst[s * 23040 + i * 3584 + 2560 + c] = v;
}

__global__ __launch_bounds__(256) void repack_wo1_kernel(
    const float* __restrict__ src, float4* __restrict__ dst)  // (256,512)
{
    const int p = blockIdx.x * 256 + threadIdx.x;   // < 32768
    const int s = p >> 12, c = p & 4095;
    const int m = c >> 8, tt = c & 255;
    const int g = tt >> 6, o = tt & 63;
    const float* b = src + (g * 64 + m * 4) * 512 + s * 64 + o;
    float4 v; v.x = b[0]; v.y = b[512]; v.z = b[1024]; v.w = b[1536];
    dst[s * 23040 + 17920 + c] = v;
}

__global__ __launch_bounds__(256) void repack_wo2_kernel(
    const float* __restrict__ src, float4* __restrict__ dst)  // (512,64)
{
    const int p = blockIdx.x * 256 + threadIdx.x;   // < 8192
    const int s = p >> 10, c = p & 1023;
    const int m = c >> 8, tt = c & 255;
    const int g = tt >> 3, o = tt & 7;
    const float* b = src + (g * 16 + m * 4) * 64 + s * 8 + o;
    float4 v; v.x = b[0]; v.y = b[64]; v.z = b[128]; v.w = b[192];
    dst[s * 23040 + 22016 + c] = v;
}

__global__ __launch_bounds__(256) void init_ctr_kernel(int* __restrict__ ctrs)
{
    const int idx = blockIdx.x * 256 + threadIdx.x;
    if (idx < 512) ctrs[idx] = 0;
}

// ---------------------------------------------------------------------------
// Decode: 64 wgs x 256 thr. element e = blk&7, slice s = blk>>3.
// Per stage: compute slice partials -> wave0 reduce -> wave0 agent-store slice
// -> release fence + signal -> prefetch next weights (overlaps spin) -> spin
// -> acquire fence -> barrier -> agent-load full vector.
// ---------------------------------------------------------------------------
__global__ __launch_bounds__(256) void decode_kernel(
    const float4* __restrict__ Wall,
    const float* __restrict__ b1, const float* __restrict__ bd,
    const float* __restrict__ b2, const float* __restrict__ bo1,
    const float* __restrict__ bo2,
    const float* __restrict__ E2, const float* __restrict__ encp,
    const float* __restrict__ h0g,
    float* __restrict__ actH, float* __restrict__ actHR,
    float* __restrict__ actX, float* __restrict__ actU,
    float* __restrict__ actLG, int* __restrict__ ctrs,
    float* __restrict__ out)
{
    const int e = blockIdx.x & 7;
    const int s = blockIdx.x >> 3;
    const int t = threadIdx.x;
    const float4* W4 = Wall + s * 23040;

    __shared__ alignas(16) float ring0[3 * CC];
    __shared__ alignas(16) float ring1[5 * CC];
    __shared__ alignas(16) float ring2[9 * CC];
    __shared__ alignas(16) float ring3[17 * CC];
    __shared__ alignas(16) float ring4[33 * CC];
    __shared__ alignas(16) float h0s[NLAYERS * CC];
    __shared__ alignas(16) float xs[C2];
    __shared__ alignas(16) float rs[C2];
    __shared__ alignas(16) float hfull[CC];
    __shared__ alignas(16) float hrf[CC];
    __shared__ alignas(16) float us[OUT_DIM];
    __shared__ float part[256];
    __shared__ int s_lab, s_stop;

    for (int i = t; i < NLAYERS * CC; i += 256) h0s[i] = h0g[i];
    if (t == 0) { s_lab = LAB_START; s_stop = MAX_T; }
    __syncthreads();

    int* ctr = ctrs + e * 64;
    int target = 8;

    float4 wA[4], wB[6], wC[4], wD[16], wE[4];

    // prefetch A weights for layer 0, step 0
    {
        const float4* p = W4;
#pragma unroll
        for (int m = 0; m < 4; ++m) wA[m] = p[m * 256 + t];
    }

    for (int k = 0; k < MAX_T; ++k) {
        // ---- x-init (replicated) ----
        {
            float xv = E2[s_lab * C2 + t] + encp[(e * MAX_T + k) * C2 + t];
            xs[t] = xv;
            rs[t] = fmaxf(xv, 0.f);
        }
        __syncthreads();

#pragma unroll
        for (int i = 0; i < NLAYERS; ++i) {
            const int d = 1 << i;
            const int rsz = (2 * d + 1);
            float* rng = (i == 0) ? ring0 : (i == 1) ? ring1 : (i == 2) ? ring2
                        : (i == 3) ? ring3 : ring4;

            // ======== Stage A: h-slice = relu(rs @ w1 + b1) ========
            {
                const int g = t >> 4;
                const float4* rs4 = (const float4*)rs;
                float acc = 0.f;
#pragma unroll
                for (int m = 0; m < 4; ++m) acc += dot4(wA[m], rs4[g * 4 + m]);
                part[t] = acc;
            }
            __syncthreads();
            if (t < 16) {
                float v = b1[i * CC + s * 16 + t];
#pragma unroll
                for (int j = 0; j < 16; ++j) v += part[t + j * 16];
                v = fmaxf(v, 0.f);
                __hip_atomic_store(&actH[e * CC + s * 16 + t], v, __ATOMIC_RELAXED, AGENT);
            }
            sync_signal(ctr, t);
            {
                const float4* p = W4 + i * 3584 + 1024;
#pragma unroll
                for (int u = 0; u < 6; ++u) wB[u] = p[u * 256 + t];
            }
            sync_wait(ctr, t, target);
            target += 8;
            if (t < CC) {
                float hv = __hip_atomic_load(&actH[e * CC + t], __ATOMIC_RELAXED, AGENT);
                hfull[t] = hv;
                rng[(k % rsz) * CC + t] = hv;
            }
            __syncthreads();

            // ======== Stage B: dilated conv slice ========
            {
                const int g = t >> 4;
                const float* p1 = (k >= d)     ? rng + ((k - d) % rsz) * CC     : h0s + i * CC;
                const float* p0 = (k >= 2 * d) ? rng + ((k - 2 * d) % rsz) * CC : h0s + i * CC;
                const float4* a0 = (const float4*)p0;
                const float4* a1 = (const float4*)p1;
                const float4* a2 = (const float4*)hfull;
                float acc = 0.f;
#pragma unroll
                for (int m = 0; m < 2; ++m) {
                    acc += dot4(wB[0 * 2 + m], a0[g * 2 + m]);
                    acc += dot4(wB[1 * 2 + m], a1[g * 2 + m]);
                    acc += dot4(wB[2 * 2 + m], a2[g * 2 + m]);
                }
                part[t] = acc;
            }
            __syncthreads();
            if (t < 16) {
                float v = bd[i * CC + s * 16 + t];
#pragma unroll
                for (int j = 0; j < 16; ++j) v += part[t + j * 16];
                v = fmaxf(v, 0.f);
                __hip_atomic_store(&actHR[e * CC + s * 16 + t], v, __ATOMIC_RELAXED, AGENT);
            }
            sync_signal(ctr, t);
            {
                const float4* p = W4 + i * 3584 + 2560;
#pragma unroll
                for (int m = 0; m < 4; ++m) wC[m] = p[m * 256 + t];
            }
            sync_wait(ctr, t, target);
            target += 8;
            if (t < CC) {
                hrf[t] = __hip_atomic_load(&actHR[e * CC + t], __ATOMIC_RELAXED, AGENT);
            }
            __syncthreads();

            // ======== Stage C: delta-slice = hrf @ w2 + b2 ========
            {
                const int g = t >> 5;
                const float4* h4 = (const float4*)hrf;
                float acc = 0.f;
#pragma unroll
                for (int m = 0; m < 4; ++m) acc += dot4(wC[m], h4[g * 4 + m]);
                part[t] = acc;
            }
            __syncthreads();
            if (t < 32) {
                float v = b2[i * C2 + s * 32 + t];
#pragma unroll
                for (int j = 0; j < 8; ++j) v += part[t + j * 32];
                __hip_atomic_store(&actX[e * C2 + s * 32 + t], v, __ATOMIC_RELAXED, AGENT);
            }
            sync_signal(ctr, t);
            if (i < 4) {
                const float4* p = W4 + (i + 1) * 3584;
#pragma unroll
                for (int m = 0; m < 4; ++m) wA[m] = p[m * 256 + t];
            } else {
                const float4* p = W4 + 17920;
#pragma unroll
                for (int m = 0; m < 16; ++m) wD[m] = p[m * 256 + t];
            }
            sync_wait(ctr, t, target);
            target += 8;
            {
                float dv = __hip_atomic_load(&actX[e * C2 + t], __ATOMIC_RELAXED, AGENT);
                float xv = xs[t] + dv;
                xs[t] = xv;
                rs[t] = fmaxf(xv, 0.f);
            }
            __syncthreads();
        }

        // ======== Stage D: u-slice = relu(xs @ wo1 + bo1) ========
        {
            const int g = t >> 6;
            const float4* x4 = (const float4*)xs;
            float acc = 0.f;
#pragma unroll
            for (int m = 0; m < 16; ++m) acc += dot4(wD[m], x4[g * 16 + m]);
            part[t] = acc;
        }
        __syncthreads();
        if (t < 64) {
            float v = bo1[s * 64 + t];
#pragma unroll
            for (int j = 0; j < 4; ++j) v += part[t + j * 64];
            v = fmaxf(v, 0.f);
            __hip_atomic_store(&actU[e * OUT_DIM + s * 64 + t], v, __ATOMIC_RELAXED, AGENT);
        }
        sync_signal(ctr, t);
        {
            const float4* p = W4 + 22016;
#pragma unroll
            for (int m = 0; m < 4; ++m) wE[m] = p[m * 256 + t];
        }
        sync_wait(ctr, t, target);
        target += 8;
        for (int idx = t; idx < OUT_DIM; idx += 256)
            us[idx] = __hip_atomic_load(&actU[e * OUT_DIM + idx], __ATOMIC_RELAXED, AGENT);
        __syncthreads();

        // ======== Stage E: logit-slice = us @ wo2 + bo2 ========
        {
            const int g = t >> 3;
            const float4* u4 = (const float4*)us;
            float acc = 0.f;
#pragma unroll
            for (int m = 0; m < 4; ++m) acc += dot4(wE[m], u4[g * 4 + m]);
            part[t] = acc;
        }
        __syncthreads();
        if (t < 8) {
            float v = bo2[s * 8 + t];
#pragma unroll
            for (int j = 0; j < 32; ++j) v += part[t + j * 8];
            __hip_atomic_store(&actLG[e * NUM_LABELS + s * 8 + t], v, __ATOMIC_RELAXED, AGENT);
        }
        sync_signal(ctr, t);
        {
            const float4* p = W4;
#pragma unroll
            for (int m = 0; m < 4; ++m) wA[m] = p[m * 256 + t];
        }
        sync_wait(ctr, t, target);
        target += 8;
        if (t < NUM_LABELS) {
            float v = __hip_atomic_load(&actLG[e * NUM_LABELS + t], __ATOMIC_RELAXED, AGENT);
            if (s == 0) out[(e * NUM_LABELS + t) * MAX_T + k] = v;
            float bv = v; int bi = t;
#pragma unroll
            for (int off = 32; off; off >>= 1) {
                float ov = __shfl_xor(bv, off);
                int oi = __shfl_xor(bi, off);
                if (ov > bv || (ov == bv && oi < bi)) { bv = ov; bi = oi; }
            }
            if (t == 0) {
                s_lab = bi;
                if (bi == LAB_STOP && s_stop == MAX_T) s_stop = k;
            }
        }
        __syncthreads();
    }

    if (s == 0 && t == 0) out[BATCH * NUM_LABELS * MAX_T + e] = (float)s_stop;
}

// ---------------------------------------------------------------------------
extern "C" void kernel_launch(void* const* d_in, const int* in_sizes, int n_in,
                              void* d_out, int out_size, void* d_ws, size_t ws_size,
                              hipStream_t stream) {
    const float* enc   = (const float*)d_in[0];
    const float* embed = (const float*)d_in[1];
    const float* w_in  = (const float*)d_in[2];
    const float* b_in  = (const float*)d_in[3];
    const float* w_enc = (const float*)d_in[4];
    const float* b_enc = (const float*)d_in[5];
    const float* w1    = (const float*)d_in[6];
    const float* b1    = (const float*)d_in[7];
    const float* wd    = (const float*)d_in[8];
    const float* bd    = (const float*)d_in[9];
    const float* w2    = (const float*)d_in[10];
    const float* b2    = (const float*)d_in[11];
    const float* wo1   = (const float*)d_in[12];
    const float* bo1   = (const float*)d_in[13];
    const float* wo2   = (const float*)d_in[14];
    const float* bo2   = (const float*)d_in[15];
    float* out = (float*)d_out;
    float* wsf = (float*)d_ws;

    float* E2   = wsf;                  // 16384 f32
    float* encp = wsf + 16384;          // 98304 f32
    float* h0   = wsf + 16384 + 98304;  // 640 f32
    // sliced weights: float4 region at 115328 f32 = 461312 B (16B aligned)
    float4* Wall = (float4*)(wsf + 115328);   // 184320 f4 = 737280 f32
    float* acts  = wsf + 115328 + 737280;     // = wsf + 852608
    float* actH  = acts;                 // 8*128
    float* actHR = actH + 1024;          // 8*128
    float* actX  = actHR + 1024;         // 8*256
    float* actU  = actX + 2048;          // 8*512
    float* actLG = actU + 4096;          // 8*64
    int*   ctrs  = (int*)(actLG + 512);  // 8*64 ints

    pre_kernel<<<NUM_LABELS + BATCH * MAX_T, 256, 0, stream>>>(
        enc, embed, w_in, b_in, w_enc, b_enc, E2, encp);
    prefix_kernel<<<1, 256, 0, stream>>>(
        embed, w_in, b_in, b_enc, w1, b1, wd, bd, w2, b2, h0);
    repack_w1_kernel<<<160, 256, 0, stream>>>(w1, Wall);
    repack_wd_kernel<<<240, 256, 0, stream>>>(wd, Wall);
    repack_w2_kernel<<<160, 256, 0, stream>>>(w2, Wall);
    repack_wo1_kernel<<<128, 256, 0, stream>>>(wo1, Wall);
    repack_wo2_kernel<<<32, 256, 0, stream>>>(wo2, Wall);
    init_ctr_kernel<<<2, 256, 0, stream>>>(ctrs);
    decode_kernel<<<64, 256, 0, stream>>>(
        Wall, b1, bd, b2, bo1, bo2, E2, encp, h0,
        actH, actHR, actX, actU, actLG, ctrs, out);
}